// Round 8
// baseline (189.212 us; speedup 1.0000x reference)
//
#include <hip/hip_runtime.h>
#include <hip/hip_bf16.h>
#include <stdint.h>

#define BB 4
#define NN 4096
#define DD 128
#define BM 32
#define BK 64

typedef __attribute__((ext_vector_type(8))) short short8;
typedef __attribute__((ext_vector_type(4))) float f32x4;

static __device__ __forceinline__ unsigned short f2bf(float f) {
  unsigned u = __builtin_bit_cast(unsigned, f);
  u += 0x7fffu + ((u >> 16) & 1u);   // round-to-nearest-even
  return (unsigned short)(u >> 16);
}

// ---------------- kernel 1: deg -> dinv (block-per-row) ----------------
__global__ __launch_bounds__(256) void k_deg(const float* __restrict__ A,
                                             float* __restrict__ dinv) {
  const int row = blockIdx.x;                 // b*N + n
  const float* a = A + (size_t)row * NN;
  float s = 0.f;
  for (int i = threadIdx.x * 4; i < NN; i += 256 * 4) {
    const float4 v = *reinterpret_cast<const float4*>(a + i);
    s += (v.x + v.y) + (v.z + v.w);
  }
  for (int off = 32; off > 0; off >>= 1) s += __shfl_down(s, off, 64);
  __shared__ float red[4];
  if ((threadIdx.x & 63) == 0) red[threadIdx.x >> 6] = s;
  __syncthreads();
  if (threadIdx.x == 0) {
    const float deg = (red[0] + red[1]) + (red[2] + red[3]) + 1.0f;
    dinv[row] = 1.0f / sqrtf(deg);
  }
}

// ---------------- kernel 2: Yt[b][d][m] = bf16(dinv[m] * X[b][m][d]) ----------------
__global__ __launch_bounds__(256) void k_prep(const float* __restrict__ X,
                                              const float* __restrict__ dinv,
                                              unsigned short* __restrict__ Yt) {
  __shared__ unsigned short tile[64][130];
  const int b = blockIdx.x >> 6;
  const int m0 = (blockIdx.x & 63) << 6;
  const float* Xb = X + ((size_t)b * NN + m0) * DD;
  const float* dv = dinv + b * NN + m0;
  for (int idx = threadIdx.x; idx < 64 * 128; idx += 256) {
    const int mi = idx >> 7, d = idx & 127;
    tile[mi][d] = f2bf(Xb[mi * DD + d] * dv[mi]);
  }
  __syncthreads();
  for (int idx = threadIdx.x; idx < 128 * 64; idx += 256) {
    const int d = idx >> 6, j = idx & 63;
    Yt[((size_t)b * DD + d) * NN + m0 + j] = tile[j][d];
  }
}

// ---------------- kernel 3: W -> bf16 ----------------
__global__ __launch_bounds__(256) void k_w(const float* __restrict__ W,
                                           unsigned short* __restrict__ Wb) {
  int idx = blockIdx.x * 1024 + threadIdx.x;
  for (int k = 0; k < 4; ++k, idx += 256) Wb[idx] = f2bf(W[idx]);
}

// ---------------- kernel 4: fused  out = dn*(A@Y + dn*X) @ W^T + b ----------------
// BM=32(n) x BN=128(d), BK=64(m). 4 waves, wave tile 32x32. grid = 512 ->
// 2 independent blocks/CU (the occupancy lever). LDS dbuf 2 x 20 KB.
// Rows are 128B (8 granules of 16B); swizzle slot = g ^ (row & 7).
__global__ __launch_bounds__(256, 2) void k_main(const float* __restrict__ A,
                                                 const unsigned short* __restrict__ Yt,
                                                 const unsigned short* __restrict__ Wb,
                                                 const float* __restrict__ X,
                                                 const float* __restrict__ dinv,
                                                 const float* __restrict__ bias,
                                                 float* __restrict__ out) {
  __shared__ char lds[40960];                  // buf k at k*20480: A @ +0 (4K), B @ +4096 (16K)

  const int tid = threadIdx.x;
  const int l   = tid & 63;
  const int wid = tid >> 6;                    // 0..3
  const int b   = blockIdx.x >> 7;
  const int n0  = (blockIdx.x & 127) << 5;

  const float* Ab = A + (size_t)(b * NN + n0) * NN;
  const unsigned short* Ytb = Yt + (size_t)b * DD * NN;

  // ---- A staging: 8 f32/thread (rows 0..31, one 16B bf16 granule each)
  const int sar = tid >> 3;                    // 0..31
  const int sag = tid & 7;                     // granule 0..7
  const float* pA = Ab + (size_t)sar * NN + sag * 8;
  float4 ra0, ra1;
  auto LOADA = [&](int t) {
    ra0 = *reinterpret_cast<const float4*>(pA + t * BK);
    ra1 = *reinterpret_cast<const float4*>(pA + t * BK + 4);
  };
  auto WRITEA = [&](int nb) {
    short8 v;
    v[0] = (short)f2bf(ra0.x); v[1] = (short)f2bf(ra0.y);
    v[2] = (short)f2bf(ra0.z); v[3] = (short)f2bf(ra0.w);
    v[4] = (short)f2bf(ra1.x); v[5] = (short)f2bf(ra1.y);
    v[6] = (short)f2bf(ra1.z); v[7] = (short)f2bf(ra1.w);
    *reinterpret_cast<short8*>(lds + nb * 20480 + sar * 128 + ((sag ^ (sar & 7)) << 4)) = v;
  };

  // ---- B staging: 64 B/thread (row tid>>1, granules yg0..yg0+3)
  const int yrow = tid >> 1;                   // 0..127
  const int yg0  = (tid & 1) << 2;             // 0 or 4
  const unsigned short* pY = Ytb + (size_t)yrow * NN + yg0 * 8;
  uint4 ry[4];
  auto LOADB = [&](int t) {
#pragma unroll
    for (int j = 0; j < 4; ++j)
      ry[j] = *reinterpret_cast<const uint4*>(pY + t * BK + j * 8);
  };
  auto WRITEB = [&](int nb) {
    char* Bs = lds + nb * 20480 + 4096 + yrow * 128;
#pragma unroll
    for (int j = 0; j < 4; ++j)
      *reinterpret_cast<uint4*>(Bs + (((yg0 + j) ^ (yrow & 7)) << 4)) = ry[j];
  };

  // ---- fragments
  const int lrow = l & 15;
  const int lg   = l >> 4;                     // 0..3
  const int ar0 = lrow, ar1 = lrow + 16;       // n rows (BM=32)
  const int br0 = wid * 32 + lrow, br1 = br0 + 16;  // d rows

  f32x4 acc[2][2] = {};
  auto GEMMSTEP = [&](int nb) {
    const char* Ap = lds + nb * 20480;
    const char* Bp = Ap + 4096;
#pragma unroll
    for (int kc = 0; kc < 2; ++kc) {
      const int g = kc * 4 + lg;
      const short8 a0 = *reinterpret_cast<const short8*>(Ap + ar0 * 128 + ((g ^ (ar0 & 7)) << 4));
      const short8 a1 = *reinterpret_cast<const short8*>(Ap + ar1 * 128 + ((g ^ (ar1 & 7)) << 4));
      const short8 b0 = *reinterpret_cast<const short8*>(Bp + br0 * 128 + ((g ^ (br0 & 7)) << 4));
      const short8 b1 = *reinterpret_cast<const short8*>(Bp + br1 * 128 + ((g ^ (br1 & 7)) << 4));
      acc[0][0] = __builtin_amdgcn_mfma_f32_16x16x32_bf16(a0, b0, acc[0][0], 0, 0, 0);
      acc[0][1] = __builtin_amdgcn_mfma_f32_16x16x32_bf16(a0, b1, acc[0][1], 0, 0, 0);
      acc[1][0] = __builtin_amdgcn_mfma_f32_16x16x32_bf16(a1, b0, acc[1][0], 0, 0, 0);
      acc[1][1] = __builtin_amdgcn_mfma_f32_16x16x32_bf16(a1, b1, acc[1][1], 0, 0, 0);
    }
  };

  // ---- prologue
  LOADA(0); LOADB(0);
  WRITEA(0); WRITEB(0);
  __syncthreads();

  int cur = 0;
  const int NT = NN / BK;                      // 64
  for (int t = 0; t < NT; ++t) {
    if (t + 1 < NT) { LOADA(t + 1); LOADB(t + 1); }   // issue-early
    GEMMSTEP(cur);
    if (t + 1 < NT) { WRITEA(cur ^ 1); WRITEB(cur ^ 1); }  // write-late
    __syncthreads();
    cur ^= 1;
  }

  // ---- epilogue 1: H = dn*(acc + dn*X) -> bf16 tile [32][256B], swizzle g^(row&15)
  const int rg = lg << 2;
  const float* Xb  = X + (size_t)(b * NN + n0) * DD;
  const float* dvb = dinv + b * NN + n0;
#pragma unroll
  for (int mi = 0; mi < 2; ++mi)
#pragma unroll
    for (int r = 0; r < 4; ++r) {
      const int nl = mi * 16 + rg + r;
      const float dn = dvb[nl];
#pragma unroll
      for (int ni = 0; ni < 2; ++ni) {
        const int d = wid * 32 + ni * 16 + lrow;
        const float h = dn * (acc[mi][ni][r] + dn * Xb[nl * DD + d]);
        *reinterpret_cast<unsigned short*>(
            lds + nl * 256 + (((d >> 3) ^ (nl & 15)) << 4) + (d & 7) * 2) = f2bf(h);
      }
    }
  __syncthreads();

  // ---- epilogue 2: out = H @ W^T + bias (K=128; W frags direct from L2-hot Wb)
  f32x4 acc2[2][2] = {};
#pragma unroll
  for (int kc = 0; kc < 4; ++kc) {
    const int g = kc * 4 + lg;
    const short8 a0 = *reinterpret_cast<const short8*>(lds + ar0 * 256 + ((g ^ (ar0 & 15)) << 4));
    const short8 a1 = *reinterpret_cast<const short8*>(lds + ar1 * 256 + ((g ^ (ar1 & 15)) << 4));
    const short8 b0 = *reinterpret_cast<const short8*>(Wb + br0 * DD + g * 8);
    const short8 b1 = *reinterpret_cast<const short8*>(Wb + br1 * DD + g * 8);
    acc2[0][0] = __builtin_amdgcn_mfma_f32_16x16x32_bf16(a0, b0, acc2[0][0], 0, 0, 0);
    acc2[0][1] = __builtin_amdgcn_mfma_f32_16x16x32_bf16(a0, b1, acc2[0][1], 0, 0, 0);
    acc2[1][0] = __builtin_amdgcn_mfma_f32_16x16x32_bf16(a1, b0, acc2[1][0], 0, 0, 0);
    acc2[1][1] = __builtin_amdgcn_mfma_f32_16x16x32_bf16(a1, b1, acc2[1][1], 0, 0, 0);
  }

  float* outb = out + (size_t)(b * NN + n0) * DD;
#pragma unroll
  for (int ni = 0; ni < 2; ++ni) {
    const int o = wid * 32 + ni * 16 + lrow;
    const float bo = bias[o];
#pragma unroll
    for (int mi = 0; mi < 2; ++mi)
#pragma unroll
      for (int r = 0; r < 4; ++r) {
        const int nl = mi * 16 + rg + r;
        outb[(size_t)nl * DD + o] = acc2[mi][ni][r] + bo;
      }
  }
}

// ---------------- host ----------------
extern "C" void kernel_launch(void* const* d_in, const int* in_sizes, int n_in,
                              void* d_out, int out_size, void* d_ws, size_t ws_size,
                              hipStream_t stream) {
  const float* X    = (const float*)d_in[0];
  const float* A    = (const float*)d_in[1];
  const float* W    = (const float*)d_in[2];
  const float* bias = (const float*)d_in[3];
  float* out = (float*)d_out;

  char* ws = (char*)d_ws;
  float* dinv = (float*)ws;                                           // 64 KB
  unsigned short* Yt = (unsigned short*)(ws + 65536);                 // 4 MB
  unsigned short* Wb = Yt + (size_t)BB * DD * NN;                     // 32 KB

  k_deg <<<BB * NN, 256, 0, stream>>>(A, dinv);
  k_w   <<<16, 256, 0, stream>>>(W, Wb);
  k_prep<<<BB * (NN / 64), 256, 0, stream>>>(X, dinv, Yt);
  k_main<<<BB * (NN / BM), 256, 0, stream>>>(A, Yt, Wb, X, dinv, bias, out);
}

// Round 9
// 131.425 us; speedup vs baseline: 1.4397x; 1.4397x over previous
//
#include <hip/hip_runtime.h>
#include <hip/hip_bf16.h>
#include <stdint.h>

#define BB 4
#define NN 4096
#define DD 128
#define BK 64

typedef __attribute__((ext_vector_type(8))) short short8;
typedef __attribute__((ext_vector_type(4))) float f32x4;

static __device__ __forceinline__ unsigned short f2bf(float f) {
  unsigned u = __builtin_bit_cast(unsigned, f);
  u += 0x7fffu + ((u >> 16) & 1u);   // round-to-nearest-even
  return (unsigned short)(u >> 16);
}

// ---------------- kernel 1: deg -> dinv (block-per-row) ----------------
__global__ __launch_bounds__(256) void k_deg(const float* __restrict__ A,
                                             float* __restrict__ dinv) {
  const int row = blockIdx.x;                 // b*N + n
  const float* a = A + (size_t)row * NN;
  float s = 0.f;
  for (int i = threadIdx.x * 4; i < NN; i += 256 * 4) {
    const float4 v = *reinterpret_cast<const float4*>(a + i);
    s += (v.x + v.y) + (v.z + v.w);
  }
  for (int off = 32; off > 0; off >>= 1) s += __shfl_down(s, off, 64);
  __shared__ float red[4];
  if ((threadIdx.x & 63) == 0) red[threadIdx.x >> 6] = s;
  __syncthreads();
  if (threadIdx.x == 0) {
    const float deg = (red[0] + red[1]) + (red[2] + red[3]) + 1.0f;
    dinv[row] = 1.0f / sqrtf(deg);
  }
}

// ---------------- kernel 2: Yt[b][d][m] = bf16(dinv[m] * X[b][m][d]) ----------------
__global__ __launch_bounds__(256) void k_prep(const float* __restrict__ X,
                                              const float* __restrict__ dinv,
                                              unsigned short* __restrict__ Yt) {
  __shared__ unsigned short tile[64][130];
  const int b = blockIdx.x >> 6;
  const int m0 = (blockIdx.x & 63) << 6;
  const float* Xb = X + ((size_t)b * NN + m0) * DD;
  const float* dv = dinv + b * NN + m0;
  for (int idx = threadIdx.x; idx < 64 * 128; idx += 256) {
    const int mi = idx >> 7, d = idx & 127;
    tile[mi][d] = f2bf(Xb[mi * DD + d] * dv[mi]);
  }
  __syncthreads();
  for (int idx = threadIdx.x; idx < 128 * 64; idx += 256) {
    const int d = idx >> 6, j = idx & 63;
    Yt[((size_t)b * DD + d) * NN + m0 + j] = tile[j][d];
  }
}

// ---------------- kernel 3: W -> bf16 ----------------
__global__ __launch_bounds__(256) void k_w(const float* __restrict__ W,
                                           unsigned short* __restrict__ Wb) {
  int idx = blockIdx.x * 1024 + threadIdx.x;
  for (int k = 0; k < 4; ++k, idx += 256) Wb[idx] = f2bf(W[idx]);
}

// ---------------- kernel 4: fused  out = dn*(A@Y + dn*X) @ W^T + b ----------------
// BM=64(n) x BN=128(d), BK=64(m). 8 waves (2x4), wave tile 32x32.
// DEPTH-3 counted-vmcnt pipeline: triple-buffered LDS, 4 VMEM instrs issued
// per iter, vmcnt(4) only (never 0 in loop) -> HBM stream never drains.
// Per-block K-ring phase de-synchronizes block fetch bursts.
__global__ __launch_bounds__(512) void k_main(const float* __restrict__ A,
                                              const unsigned short* __restrict__ Yt,
                                              const unsigned short* __restrict__ Wb,
                                              const float* __restrict__ X,
                                              const float* __restrict__ dinv,
                                              const float* __restrict__ bias,
                                              float* __restrict__ out) {
  // bufA j: j*8192 ([64][128B]); bufB j: 24576 + j*16384 ([128][128B])
  __shared__ char lds[73728];

  const int tid = threadIdx.x;
  const int l   = tid & 63;
  const int wid = tid >> 6;
  const int b   = blockIdx.x >> 6;
  const int n0  = (blockIdx.x & 63) << 6;
  const int wr  = wid >> 2;     // 0..1
  const int wc  = wid & 3;      // 0..3
  const int phase = (blockIdx.x * 29) & 63;    // K-ring offset

  const float* Ab = A + (size_t)(b * NN + n0) * NN;
  const unsigned short* Ytb = Yt + (size_t)b * DD * NN;

  // ---- A staging: 8 f32/thread (row sar, 16B-granule sag)
  const int sar = tid >> 3;                    // 0..63
  const int sag = tid & 7;                     // 0..7
  const float* pA = Ab + (size_t)sar * NN + sag * 8;
  const int awrel = sar * 128 + ((sag ^ (sar & 7)) << 4);

  // ---- B staging (global_load_lds): 2 instrs/wave, 8 rows each
  const int brow = wid * 16 + (l >> 3);        // rows for instr 0; +8 for instr 1
  const int bgr  = ((l & 7) ^ (l >> 3)) << 3;  // pre-swizzled source granule (halves)
  const unsigned short* pB0 = Ytb + (size_t)brow * NN + bgr;
  const unsigned short* pB1 = Ytb + (size_t)(brow + 8) * NN + bgr;

  // ---- fragment geometry
  const int lrow = l & 15;
  const int lg   = l >> 4;
  const int ar0 = wr * 32 + lrow, ar1 = ar0 + 16;
  const int br0 = wc * 32 + lrow, br1 = br0 + 16;

  f32x4 acc[2][2] = {};

#define TPH(t) (((t) + phase) & 63)
#define LOADA(t, s0, s1)                                                    \
  { const int c_ = TPH(t) * BK;                                             \
    s0 = *reinterpret_cast<const float4*>(pA + c_);                         \
    s1 = *reinterpret_cast<const float4*>(pA + c_ + 4); }
#define GLDSB(t, boff)                                                      \
  { const size_t c_ = (size_t)TPH(t) * BK;                                  \
    char* d_ = lds + (boff) + wid * 2048;                                   \
    __builtin_amdgcn_global_load_lds(pB0 + c_, d_, 16, 0, 0);               \
    __builtin_amdgcn_global_load_lds(pB1 + c_, d_ + 1024, 16, 0, 0); }
#define CVTA(s0, s1, aoff)                                                  \
  { short8 v_;                                                              \
    v_[0] = (short)f2bf(s0.x); v_[1] = (short)f2bf(s0.y);                   \
    v_[2] = (short)f2bf(s0.z); v_[3] = (short)f2bf(s0.w);                   \
    v_[4] = (short)f2bf(s1.x); v_[5] = (short)f2bf(s1.y);                   \
    v_[6] = (short)f2bf(s1.z); v_[7] = (short)f2bf(s1.w);                   \
    *reinterpret_cast<short8*>(lds + (aoff) + awrel) = v_; }
#define GEMMSTEP(aoff, boff)                                                \
  { const char* Ap_ = lds + (aoff);                                         \
    const char* Bp_ = lds + (boff);                                         \
    _Pragma("unroll")                                                       \
    for (int kc = 0; kc < 2; ++kc) {                                        \
      const int g_ = kc * 4 + lg;                                           \
      const short8 a0 = *reinterpret_cast<const short8*>(Ap_ + ar0 * 128 + ((g_ ^ (ar0 & 7)) << 4)); \
      const short8 a1 = *reinterpret_cast<const short8*>(Ap_ + ar1 * 128 + ((g_ ^ (ar1 & 7)) << 4)); \
      const short8 b0 = *reinterpret_cast<const short8*>(Bp_ + br0 * 128 + ((g_ ^ (br0 & 7)) << 4)); \
      const short8 b1 = *reinterpret_cast<const short8*>(Bp_ + br1 * 128 + ((g_ ^ (br1 & 7)) << 4)); \
      acc[0][0] = __builtin_amdgcn_mfma_f32_16x16x32_bf16(a0, b0, acc[0][0], 0, 0, 0); \
      acc[0][1] = __builtin_amdgcn_mfma_f32_16x16x32_bf16(a0, b1, acc[0][1], 0, 0, 0); \
      acc[1][0] = __builtin_amdgcn_mfma_f32_16x16x32_bf16(a1, b0, acc[1][0], 0, 0, 0); \
      acc[1][1] = __builtin_amdgcn_mfma_f32_16x16x32_bf16(a1, b1, acc[1][1], 0, 0, 0); } }
#define VMCNT4   asm volatile("s_waitcnt vmcnt(4)" ::: "memory")
#define LGKM0    asm volatile("s_waitcnt lgkmcnt(0)" ::: "memory")
#define BARRIER  { __builtin_amdgcn_s_barrier(); __builtin_amdgcn_sched_barrier(0); }

  float4 e0, e1, o0, o1;                       // A reg sets (even/odd)
  const int NT = NN / BK;                      // 64

  // ---- prologue: A0,B0,A1,B1 in flight (8); finish A0/B0; publish buf0
  LOADA(0, e0, e1);
  GLDSB(0, 24576);
  LOADA(1, o0, o1);
  GLDSB(1, 24576 + 16384);
  VMCNT4;                                      // A0 regs + B0 landed
  CVTA(e0, e1, 0);
  LGKM0;
  BARRIER;

  int a0o = 0, a1o = 8192, a2o = 16384;
  int b0o = 24576, b1o = 24576 + 16384, b2o = 24576 + 32768;

  for (int t = 0; t < NT; t += 2) {
    // even step: read (a0o,b0o); issue t+2 -> (e regs, b2o); cvt o regs -> a1o
    { const int tn = (t + 2 < NT) ? t + 2 : NT - 1;
      LOADA(tn, e0, e1);
      GLDSB(tn, b2o); }
    GEMMSTEP(a0o, b0o);
    VMCNT4;                                    // A(t+1) regs + B(t+1) landed
    CVTA(o0, o1, a1o);
    LGKM0;
    BARRIER;
    // odd step: read (a1o,b1o); issue t+3 -> (o regs, b0o); cvt e regs -> a2o
    { const int tn = (t + 3 < NT) ? t + 3 : NT - 1;
      LOADA(tn, o0, o1);
      GLDSB(tn, b0o); }
    GEMMSTEP(a1o, b1o);
    VMCNT4;
    CVTA(e0, e1, a2o);
    LGKM0;
    BARRIER;
    // rotate buffers by 2 (mod 3)
    int ta = a0o; a0o = a2o; a2o = a1o; a1o = ta;
    int tb = b0o; b0o = b2o; b2o = b1o; b1o = tb;
  }

  // ---- epilogue 1: H = dn*(acc + dn*X) -> bf16 [64][256B] at lds+0 (swz g^(row&15))
  const int rg = lg << 2;
  const float* Xb  = X + (size_t)(b * NN + n0) * DD;
  const float* dvb = dinv + b * NN + n0;
#pragma unroll
  for (int mi = 0; mi < 2; ++mi)
#pragma unroll
    for (int r = 0; r < 4; ++r) {
      const int nl = wr * 32 + mi * 16 + rg + r;
      const float dn = dvb[nl];
#pragma unroll
      for (int ni = 0; ni < 2; ++ni) {
        const int d = wc * 32 + ni * 16 + lrow;
        const float h = dn * (acc[mi][ni][r] + dn * Xb[nl * DD + d]);
        *reinterpret_cast<unsigned short*>(
            lds + nl * 256 + (((d >> 3) ^ (nl & 15)) << 4) + (d & 7) * 2) = f2bf(h);
      }
    }
  LGKM0;
  BARRIER;

  // ---- epilogue 2: out = H @ W^T + bias (K=128; W fragments direct from Wb)
  f32x4 acc2[2][2] = {};
#pragma unroll
  for (int kc = 0; kc < 4; ++kc) {
    const int g = kc * 4 + lg;
    const short8 a0 = *reinterpret_cast<const short8*>(lds + ar0 * 256 + ((g ^ (ar0 & 15)) << 4));
    const short8 a1 = *reinterpret_cast<const short8*>(lds + ar1 * 256 + ((g ^ (ar1 & 15)) << 4));
    const short8 b0 = *reinterpret_cast<const short8*>(Wb + br0 * DD + g * 8);
    const short8 b1 = *reinterpret_cast<const short8*>(Wb + br1 * DD + g * 8);
    acc2[0][0] = __builtin_amdgcn_mfma_f32_16x16x32_bf16(a0, b0, acc2[0][0], 0, 0, 0);
    acc2[0][1] = __builtin_amdgcn_mfma_f32_16x16x32_bf16(a0, b1, acc2[0][1], 0, 0, 0);
    acc2[1][0] = __builtin_amdgcn_mfma_f32_16x16x32_bf16(a1, b0, acc2[1][0], 0, 0, 0);
    acc2[1][1] = __builtin_amdgcn_mfma_f32_16x16x32_bf16(a1, b1, acc2[1][1], 0, 0, 0);
  }

  float* outb = out + (size_t)(b * NN + n0) * DD;
#pragma unroll
  for (int ni = 0; ni < 2; ++ni) {
    const int o = wc * 32 + ni * 16 + lrow;
    const float bo = bias[o];
#pragma unroll
    for (int mi = 0; mi < 2; ++mi)
#pragma unroll
      for (int r = 0; r < 4; ++r) {
        const int nl = wr * 32 + mi * 16 + rg + r;
        outb[(size_t)nl * DD + o] = acc2[mi][ni][r] + bo;
      }
  }
#undef TPH
#undef LOADA
#undef GLDSB
#undef CVTA
#undef GEMMSTEP
#undef VMCNT4
#undef LGKM0
#undef BARRIER
}

// ---------------- host ----------------
extern "C" void kernel_launch(void* const* d_in, const int* in_sizes, int n_in,
                              void* d_out, int out_size, void* d_ws, size_t ws_size,
                              hipStream_t stream) {
  const float* X    = (const float*)d_in[0];
  const float* A    = (const float*)d_in[1];
  const float* W    = (const float*)d_in[2];
  const float* bias = (const float*)d_in[3];
  float* out = (float*)d_out;

  char* ws = (char*)d_ws;
  float* dinv = (float*)ws;                                           // 64 KB
  unsigned short* Yt = (unsigned short*)(ws + 65536);                 // 4 MB
  unsigned short* Wb = Yt + (size_t)BB * DD * NN;                     // 32 KB

  k_deg <<<BB * NN, 256, 0, stream>>>(A, dinv);
  k_w   <<<16, 256, 0, stream>>>(W, Wb);
  k_prep<<<BB * (NN / 64), 256, 0, stream>>>(X, dinv, Yt);
  k_main<<<BB * (NN / 64), 512, 0, stream>>>(A, Yt, Wb, X, dinv, bias, out);
}

// Round 10
// 118.779 us; speedup vs baseline: 1.5930x; 1.1065x over previous
//
#include <hip/hip_runtime.h>
#include <hip/hip_bf16.h>
#include <stdint.h>

#define BB 4
#define NN 4096
#define DD 128

typedef __attribute__((ext_vector_type(8))) short short8;
typedef __attribute__((ext_vector_type(4))) float f32x4;

static __device__ __forceinline__ unsigned short f2bf(float f) {
  unsigned u = __builtin_bit_cast(unsigned, f);
  u += 0x7fffu + ((u >> 16) & 1u);   // round-to-nearest-even
  return (unsigned short)(u >> 16);
}

// ---------------- kernel 1: deg -> dinv (block-per-row) ----------------
__global__ __launch_bounds__(256) void k_deg(const float* __restrict__ A,
                                             float* __restrict__ dinv) {
  const int row = blockIdx.x;                 // b*N + n
  const float* a = A + (size_t)row * NN;
  float s = 0.f;
  for (int i = threadIdx.x * 4; i < NN; i += 256 * 4) {
    const float4 v = *reinterpret_cast<const float4*>(a + i);
    s += (v.x + v.y) + (v.z + v.w);
  }
  for (int off = 32; off > 0; off >>= 1) s += __shfl_down(s, off, 64);
  __shared__ float red[4];
  if ((threadIdx.x & 63) == 0) red[threadIdx.x >> 6] = s;
  __syncthreads();
  if (threadIdx.x == 0) {
    const float deg = (red[0] + red[1]) + (red[2] + red[3]) + 1.0f;
    dinv[row] = 1.0f / sqrtf(deg);
  }
}

// ---------------- kernel 2: W -> bf16 ----------------
__global__ __launch_bounds__(256) void k_w(const float* __restrict__ W,
                                           unsigned short* __restrict__ Wb) {
  int idx = blockIdx.x * 1024 + threadIdx.x;
  for (int k = 0; k < 4; ++k, idx += 256) Wb[idx] = f2bf(W[idx]);
}

// ---------------- kernel 3: V = (d*X) @ W^T ; Vt bf16 [B][O][M] ; Vr2 = d*V + bias (f32) ----------------
// 256 threads, 4 waves (2x2), block tile 64(m) x 128(o), K=128.
__global__ __launch_bounds__(256) void k_zv(const float* __restrict__ X,
                                            const float* __restrict__ dinv,
                                            const unsigned short* __restrict__ Wb,
                                            const float* __restrict__ bias,
                                            unsigned short* __restrict__ Vt,
                                            float* __restrict__ Vr2) {
  __shared__ char lds[65792];   // Ys [64][256B] @0, Ws [128][256B] @16384, vt ushort[64][130] @49152
  unsigned short* vt = (unsigned short*)(lds + 49152);

  const int tid = threadIdx.x;
  const int l   = tid & 63;
  const int wid = tid >> 6;
  const int b   = blockIdx.x >> 6;
  const int m0  = (blockIdx.x & 63) << 6;
  const float* Xb  = X + ((size_t)b * NN + m0) * DD;
  const float* dvb = dinv + b * NN + m0;

  // stage Ys = bf16(d_m * X) , 256B rows, slot = g ^ (row&15)
  {
    const int row = tid >> 2;
    const int cb  = (tid & 3) * 32;
    const float dv = dvb[row];
    char* Ys = lds + row * 256;
#pragma unroll
    for (int j = 0; j < 4; ++j) {
      const float4 v0 = *reinterpret_cast<const float4*>(Xb + row * DD + cb + j * 8);
      const float4 v1 = *reinterpret_cast<const float4*>(Xb + row * DD + cb + j * 8 + 4);
      short8 v;
      v[0] = (short)f2bf(v0.x * dv); v[1] = (short)f2bf(v0.y * dv);
      v[2] = (short)f2bf(v0.z * dv); v[3] = (short)f2bf(v0.w * dv);
      v[4] = (short)f2bf(v1.x * dv); v[5] = (short)f2bf(v1.y * dv);
      v[6] = (short)f2bf(v1.z * dv); v[7] = (short)f2bf(v1.w * dv);
      const int g = (tid & 3) * 4 + j;
      *reinterpret_cast<short8*>(Ys + ((g ^ (row & 15)) << 4)) = v;
    }
  }
  // stage Ws from Wb (bf16), 256B rows, same swizzle
  {
    const int row = tid >> 1;
    const int gb  = (tid & 1) * 8;
    char* Ws = lds + 16384 + row * 256;
#pragma unroll
    for (int j = 0; j < 8; ++j) {
      const uint4 v = *reinterpret_cast<const uint4*>(Wb + row * DD + (gb + j) * 8);
      *reinterpret_cast<uint4*>(Ws + (((gb + j) ^ (row & 15)) << 4)) = v;
    }
  }
  __syncthreads();

  const int lrow = l & 15, lg = l >> 4;
  const int wr = wid >> 1, wc = wid & 1;
  const int ar0 = wr * 32 + lrow, ar1 = ar0 + 16;
  f32x4 acc[2][4] = {};
#pragma unroll
  for (int kc = 0; kc < 4; ++kc) {
    const int g = kc * 4 + lg;
    const short8 a0 = *reinterpret_cast<const short8*>(lds + ar0 * 256 + ((g ^ (ar0 & 15)) << 4));
    const short8 a1 = *reinterpret_cast<const short8*>(lds + ar1 * 256 + ((g ^ (ar1 & 15)) << 4));
#pragma unroll
    for (int ni = 0; ni < 4; ++ni) {
      const int br = wc * 64 + ni * 16 + lrow;
      const short8 bb = *reinterpret_cast<const short8*>(lds + 16384 + br * 256 + ((g ^ (br & 15)) << 4));
      acc[0][ni] = __builtin_amdgcn_mfma_f32_16x16x32_bf16(a0, bb, acc[0][ni], 0, 0, 0);
      acc[1][ni] = __builtin_amdgcn_mfma_f32_16x16x32_bf16(a1, bb, acc[1][ni], 0, 0, 0);
    }
  }

  const int rg = lg << 2;
#pragma unroll
  for (int mi = 0; mi < 2; ++mi)
#pragma unroll
    for (int r = 0; r < 4; ++r) {
      const int ml = wr * 32 + mi * 16 + rg + r;
      const float dm = dvb[ml];
#pragma unroll
      for (int ni = 0; ni < 4; ++ni) {
        const int o = wc * 64 + ni * 16 + lrow;
        const float z = acc[mi][ni][r];
        vt[ml * 130 + o] = f2bf(z);
        Vr2[((size_t)(b * NN + m0 + ml)) * DD + o] = dm * z + bias[o];
      }
    }
  __syncthreads();

  // Vt[b][o][m0..m0+63] coalesced store via LDS transpose
  {
    const int o = tid >> 1, mc = (tid & 1) * 32;
    unsigned w[16];
#pragma unroll
    for (int j = 0; j < 16; ++j)
      w[j] = (unsigned)vt[(mc + 2 * j) * 130 + o] | ((unsigned)vt[(mc + 2 * j + 1) * 130 + o] << 16);
    unsigned short* dst = Vt + ((size_t)b * DD + o) * NN + m0 + mc;
#pragma unroll
    for (int q = 0; q < 4; ++q) {
      uint4 u; u.x = w[q*4]; u.y = w[q*4+1]; u.z = w[q*4+2]; u.w = w[q*4+3];
      *reinterpret_cast<uint4*>(dst + q * 8) = u;
    }
  }
}

// ---------------- kernel 4: out = d_n*(A @ V) + Vr2   (R2-proven loop) ----------------
// BM=64 x BN=128, BK=64. 8 waves (2x4), 32x32/wave. LDS dbuf 48KB.
__global__ __launch_bounds__(512) void k_main(const float* __restrict__ A,
                                              const unsigned short* __restrict__ Vt,
                                              const float* __restrict__ Vr2,
                                              const float* __restrict__ dinv,
                                              float* __restrict__ out) {
  __shared__ char lds[49152];   // A dbuf 2x8K @0,8192 ; B dbuf 2x16K @16384,32768

  const int tid = threadIdx.x;
  const int l   = tid & 63;
  const int wid = tid >> 6;
  const int b   = blockIdx.x >> 6;
  const int n0  = (blockIdx.x & 63) << 6;
  const int wr  = wid >> 2;     // 0..1
  const int wc  = wid & 3;      // 0..3

  const float* Ab = A + (size_t)(b * NN + n0) * NN;
  const unsigned short* Vtb = Vt + (size_t)b * DD * NN;

  // A staging: 2 float4 / thread
  const int sar0 = tid >> 4;                   // 0..31
  const int sar1 = sar0 + 32;
  const int ac4  = (tid & 15) << 2;            // f32 col 0..60
  const int aw0  = sar0 * 128 + ((ac4 << 1) ^ ((sar0 & 7) << 4));
  const int aw1  = sar1 * 128 + ((ac4 << 1) ^ ((sar1 & 7) << 4));

  // B (Vt) staging: 2 x 16B / thread
  const int yr0 = tid >> 3;                    // 0..63
  const int yr1 = yr0 + 64;                    // 64..127
  const int yc  = (tid & 7) << 4;              // byte col 0..112
  const int yw0 = yr0 * 128 + (yc ^ ((yr0 & 7) << 4));
  const int yw1 = yr1 * 128 + (yc ^ ((yr1 & 7) << 4));

  float4 ra0, ra1;
  uint4  ry0, ry1;

  auto LOAD = [&](int t) {
    ra0 = *reinterpret_cast<const float4*>(Ab + (size_t)sar0 * NN + t * 64 + ac4);
    ra1 = *reinterpret_cast<const float4*>(Ab + (size_t)sar1 * NN + t * 64 + ac4);
    ry0 = *reinterpret_cast<const uint4*>(Vtb + (size_t)yr0 * NN + t * 64 + (yc >> 1));
    ry1 = *reinterpret_cast<const uint4*>(Vtb + (size_t)yr1 * NN + t * 64 + (yc >> 1));
  };
  auto WRITE = [&](int nb) {
    char* As = lds + nb * 8192;
    char* Ys = lds + 16384 + nb * 16384;
    *reinterpret_cast<ushort4*>(As + aw0) =
        make_ushort4(f2bf(ra0.x), f2bf(ra0.y), f2bf(ra0.z), f2bf(ra0.w));
    *reinterpret_cast<ushort4*>(As + aw1) =
        make_ushort4(f2bf(ra1.x), f2bf(ra1.y), f2bf(ra1.z), f2bf(ra1.w));
    *reinterpret_cast<uint4*>(Ys + yw0) = ry0;
    *reinterpret_cast<uint4*>(Ys + yw1) = ry1;
  };

  f32x4 acc[2][2] = {};
  const int lrow = l & 15;
  const int lk16 = (l >> 4) << 4;

  const int arow0 = wr * 32 + lrow, arow1 = arow0 + 16;
  const int brow0 = wc * 32 + lrow, brow1 = brow0 + 16;
  const int abase0 = arow0 * 128, abase1 = arow1 * 128;
  const int bbase0 = brow0 * 128, bbase1 = brow1 * 128;
  const int amsk0 = (arow0 & 7) << 4, amsk1 = (arow1 & 7) << 4;
  const int bmsk0 = (brow0 & 7) << 4, bmsk1 = (brow1 & 7) << 4;

  LOAD(0);
  WRITE(0);
  __syncthreads();
  int cur = 0;
  const int NT = NN / 64;
  for (int t = 0; t < NT; ++t) {
    if (t + 1 < NT) LOAD(t + 1);               // issue-early
    const char* As_ = lds + cur * 8192;
    const char* Ys_ = lds + 16384 + cur * 16384;
#pragma unroll
    for (int ks = 0; ks < 2; ++ks) {
      const int kb = ks * 64 + lk16;
      const short8 a0 = *reinterpret_cast<const short8*>(As_ + abase0 + (kb ^ amsk0));
      const short8 a1 = *reinterpret_cast<const short8*>(As_ + abase1 + (kb ^ amsk1));
      const short8 b0 = *reinterpret_cast<const short8*>(Ys_ + bbase0 + (kb ^ bmsk0));
      const short8 b1 = *reinterpret_cast<const short8*>(Ys_ + bbase1 + (kb ^ bmsk1));
      acc[0][0] = __builtin_amdgcn_mfma_f32_16x16x32_bf16(a0, b0, acc[0][0], 0, 0, 0);
      acc[0][1] = __builtin_amdgcn_mfma_f32_16x16x32_bf16(a0, b1, acc[0][1], 0, 0, 0);
      acc[1][0] = __builtin_amdgcn_mfma_f32_16x16x32_bf16(a1, b0, acc[1][0], 0, 0, 0);
      acc[1][1] = __builtin_amdgcn_mfma_f32_16x16x32_bf16(a1, b1, acc[1][1], 0, 0, 0);
    }
    if (t + 1 < NT) WRITE(cur ^ 1);            // write-late
    __syncthreads();
    cur ^= 1;
  }

  // epilogue: out = d_n * acc + Vr2   (identity + bias already folded into Vr2)
  const int rg = (l >> 4) << 2;
#pragma unroll
  for (int mi = 0; mi < 2; ++mi)
#pragma unroll
    for (int r = 0; r < 4; ++r) {
      const int n = n0 + wr * 32 + mi * 16 + rg + r;
      const float dn = dinv[b * NN + n];
#pragma unroll
      for (int ni = 0; ni < 2; ++ni) {
        const int o = wc * 32 + ni * 16 + lrow;
        const size_t gi = (size_t)(b * NN + n) * DD + o;
        out[gi] = dn * acc[mi][ni][r] + Vr2[gi];
      }
    }
}

// ---------------- host ----------------
extern "C" void kernel_launch(void* const* d_in, const int* in_sizes, int n_in,
                              void* d_out, int out_size, void* d_ws, size_t ws_size,
                              hipStream_t stream) {
  const float* X    = (const float*)d_in[0];
  const float* A    = (const float*)d_in[1];
  const float* W    = (const float*)d_in[2];
  const float* bias = (const float*)d_in[3];
  float* out = (float*)d_out;

  char* ws = (char*)d_ws;
  float* dinv = (float*)ws;                                           // 64 KB
  unsigned short* Wb = (unsigned short*)(ws + 65536);                 // 32 KB
  unsigned short* Vt = Wb + 32768 / 2;                                // 4 MB  [B][O][M]
  float* Vr2 = (float*)((char*)Vt + (size_t)BB * DD * NN * 2);        // 8 MB  [B][M][O]

  k_w   <<<16, 256, 0, stream>>>(W, Wb);
  k_deg <<<BB * NN, 256, 0, stream>>>(A, dinv);
  k_zv  <<<BB * (NN / 64), 256, 0, stream>>>(X, dinv, Wb, bias, Vt, Vr2);
  k_main<<<BB * (NN / 64), 512, 0, stream>>>(A, Vt, Vr2, dinv, out);
}